// Round 8
// baseline (134.796 us; speedup 1.0000x reference)
//
#include <hip/hip_runtime.h>
#include <hip/hip_bf16.h>

// LSTM_71382356459716 R7: R6 + two stall-targeted changes (minimal diff).
// R6 counters: busy 33us (trans-floor ~30us, formulation-independent -- Pade/
// shared-rcp variants all cost the same once full-rate muls are charged),
// stall 26us. Theory: LOCKSTEP RESONANCE -- 4 identical blocks/CU start
// simultaneously, so per-step latency gaps (post-barrier ds_read ~120cyc,
// MFMA dep chain, activation chains) align across the 4 waves on each SIMD
// and nothing fills them. Changes:
//  (1) entry de-phase: blocks sleep hash(blockIdx)&7 x ~128cyc, spreading
//      barrier-group phase across a step.
//  (2) stager rebalance: staging lanes = lanes 0..27 of EVERY wave (was
//      tid<112 = waves 0-1 only), so no wave is critical-path-heavier.
// Kept from R6: 1024 blocks x 4 waves, wave owns 16 units (4 M-tiles
// stationary in regs, bias folded into W col 28 vs constant-1 x column),
// 16 rows/block, two-deep x prefetch through 112 stagers, double-buffered
// LDS rows of 104 shorts, 3 conflict-free ds_read_b128 B-frags, 1 barrier,
// exp-form activations.

namespace {
constexpr int B_TOT   = 16384;
constexpr int T_STEPS = 28;
constexpr int IN_DIM  = 28;
constexpr int HID     = 64;
constexpr int OUT_DIM = 10;
constexpr int ROWS    = 16;    // batch rows per block -> 1024 blocks, 4/CU
constexpr int THREADS = 256;   // 4 waves
constexpr int KP      = 104;   // row stride in shorts (208 B, odd*16B)
constexpr int XROW    = T_STEPS * IN_DIM;  // 784 floats per batch row
}

typedef __attribute__((ext_vector_type(8))) short short8v;   // 8 bf16
typedef __attribute__((ext_vector_type(4))) short short4v;
typedef __attribute__((ext_vector_type(4))) float float4v;

__device__ __forceinline__ short f2bf_cold(float f) {   // init path only
  union { float f; unsigned u; } v; v.f = f;
  unsigned r = v.u + 0x7FFFu + ((v.u >> 16) & 1u);
  return (short)(r >> 16);
}
__device__ __forceinline__ float bf2f(short s) {
  union { unsigned u; float f; } v; v.u = ((unsigned)(unsigned short)s) << 16;
  return v.f;
}
__device__ __forceinline__ unsigned pk2(float a, float b) {  // 2xf32->bf16x2
  __hip_bfloat162 h = __float22bfloat162_rn(float2{a, b});
  union { __hip_bfloat162 h; unsigned u; } cv; cv.h = h; return cv.u;
}
__device__ __forceinline__ float sigf(float v) {
  return __builtin_amdgcn_rcpf(1.0f + __expf(-v));
}
__device__ __forceinline__ float tanh_f(float v) {
  return 2.0f * __builtin_amdgcn_rcpf(1.0f + __expf(-2.0f * v)) - 1.0f;
}

__global__ __attribute__((amdgpu_flat_work_group_size(THREADS, THREADS),
                          amdgpu_waves_per_eu(4, 4)))
void lstm_mfma7(const float* __restrict__ x, const float* __restrict__ W_ih,
                const float* __restrict__ W_hh, const float* __restrict__ b_ih,
                const float* __restrict__ b_hh, const float* __restrict__ W_fc,
                const float* __restrict__ b_fc, float* __restrict__ out) {
  __shared__ short hs[2][ROWS][KP];   // [buf][row][k]: 0..27 x, 28 = 1.0, 32..95 h

  const int tid  = threadIdx.x;
  const int lane = tid & 63;
  const int w    = tid >> 6;      // wave 0..3 -> units 16w..16w+15
  const int l15  = lane & 15;
  const int q    = lane >> 4;     // 0..3
  const int b0   = blockIdx.x * ROWS;

  // ---- (1) de-phase blocks to break cross-block lockstep -------------------
  {
    const unsigned bi = blockIdx.x;
    const unsigned ph = (bi ^ (bi >> 3) ^ (bi >> 6)) & 7u;
    for (unsigned i = 0; i < ph; ++i) __builtin_amdgcn_s_sleep(2);  // ~128cyc ea
  }

  // ---- stationary A (weights + bias col 28), gate rows permuted unit-major
  // A-frag: lane holds A[m = 16*mt + l15][k = kc*32 + q*8 + j].
  short8v a[4][3];
#pragma unroll
  for (int i = 0; i < 4; ++i) {
    const int mt   = 4 * w + i;
    const int m    = 16 * mt + l15;
    const int unit = m >> 2, type = m & 3;
    const int g    = type * 64 + unit;
#pragma unroll
    for (int kc = 0; kc < 3; ++kc) {
      short8v frag;
#pragma unroll
      for (int j = 0; j < 8; ++j) {
        const int k = kc * 32 + q * 8 + j;
        float v = 0.0f;
        if (k < IN_DIM)        v = W_ih[g * IN_DIM + k];
        else if (k == IN_DIM)  v = b_ih[g] + b_hh[g];     // bias column
        else if (k >= 32)      v = W_hh[g * HID + (k - 32)];
        frag[j] = f2bf_cold(v);
      }
      a[i][kc] = frag;
    }
  }

  // zero both buffers, then set the constant bias column (never overwritten)
  for (int idx = tid; idx < 2 * ROWS * KP; idx += THREADS) (&hs[0][0][0])[idx] = 0;
  __syncthreads();
  if (tid < 2 * ROWS) hs[tid >> 4][tid & 15][IN_DIM] = (short)0x3F80;  // bf16 1.0

  // ---- (2) x staging balanced across waves: lanes 0..27 of each wave -------
  // global slot s = w*28 + lane -> row s/7 (wave w owns rows 4w..4w+3),
  // col-group s%7 -> k = 4*sc..4*sc+3.
  const bool stager = (lane < 28);
  const int  s  = w * 28 + lane;
  const int  sr = s / 7;
  const int  sc = s - 7 * sr;
  const float* xptr = x + (size_t)(b0 + sr) * XROW + sc * 4;

  // stage x_0 directly; preload x_1 into the in-flight register
  float4 xfly = {0.f, 0.f, 0.f, 0.f};
  if (stager) {
    float4 x0 = *(const float4*)xptr;
    short4v sv;
    unsigned plo = pk2(x0.x, x0.y), phi = pk2(x0.z, x0.w);
    sv[0] = (short)(plo & 0xFFFF); sv[1] = (short)(plo >> 16);
    sv[2] = (short)(phi & 0xFFFF); sv[3] = (short)(phi >> 16);
    *(short4v*)&hs[0][sr][sc * 4] = sv;
    xfly = *(const float4*)(xptr + 1 * IN_DIM);   // x_1, consumed at t=0
  }
  __syncthreads();

  float c_state[4] = {0.f, 0.f, 0.f, 0.f};

  for (int t = 0; t < T_STEPS; ++t) {
    const int cur = t & 1, nxt = cur ^ 1;

    // B-frags: lane holds B[k = kc*32 + q*8 + j][n = l15]
    short8v bf0 = *(const short8v*)&hs[cur][l15][q * 8];
    short8v bf1 = *(const short8v*)&hs[cur][l15][32 + q * 8];
    short8v bf2 = *(const short8v*)&hs[cur][l15][64 + q * 8];

    // store x_{t+1} (loaded a full step ago -> vmcnt long since retired),
    // then issue the load of x_{t+2} (consumed next step).
    if (stager) {
      if (t + 1 < T_STEPS) {
        short4v sv;
        unsigned plo = pk2(xfly.x, xfly.y), phi = pk2(xfly.z, xfly.w);
        sv[0] = (short)(plo & 0xFFFF); sv[1] = (short)(plo >> 16);
        sv[2] = (short)(phi & 0xFFFF); sv[3] = (short)(phi >> 16);
        *(short4v*)&hs[nxt][sr][sc * 4] = sv;
      }
      if (t + 2 < T_STEPS)
        xfly = *(const float4*)(xptr + (t + 2) * IN_DIM);
    }

    const float4v zero4 = {0.f, 0.f, 0.f, 0.f};
    float4v acc[4];
#pragma unroll
    for (int i = 0; i < 4; ++i)
      acc[i] = __builtin_amdgcn_mfma_f32_16x16x32_bf16(a[i][0], bf0, zero4, 0, 0, 0);
#pragma unroll
    for (int i = 0; i < 4; ++i)
      acc[i] = __builtin_amdgcn_mfma_f32_16x16x32_bf16(a[i][1], bf1, acc[i], 0, 0, 0);
#pragma unroll
    for (int i = 0; i < 4; ++i)
      acc[i] = __builtin_amdgcn_mfma_f32_16x16x32_bf16(a[i][2], bf2, acc[i], 0, 0, 0);

    // activations + state update; lane-local (regs 0..3 = i,f,g,o of one unit)
    float hv[4];
#pragma unroll
    for (int i = 0; i < 4; ++i) {
      float4v g4 = acc[i];
      float iv = sigf(g4[0]);
      float fv = sigf(g4[1]);
      float gv = tanh_f(g4[2]);
      float ov = sigf(g4[3]);
      float cn = fv * c_state[i] + iv * gv;
      c_state[i] = cn;
      hv[i] = ov * tanh_f(cn);
    }
    // packed bf16 convert, 4 b16 stores (unit 16w+4i+q, row l15)
    unsigned p01 = pk2(hv[0], hv[1]);
    unsigned p23 = pk2(hv[2], hv[3]);
    hs[nxt][l15][32 + 16 * w + 0 + q]  = (short)(p01 & 0xFFFF);
    hs[nxt][l15][32 + 16 * w + 4 + q]  = (short)(p01 >> 16);
    hs[nxt][l15][32 + 16 * w + 8 + q]  = (short)(p23 & 0xFFFF);
    hs[nxt][l15][32 + 16 * w + 12 + q] = (short)(p23 >> 16);

    __syncthreads();
  }

  // ---- FC epilogue: final h in hs[0] (t=27 wrote nxt = 0), cols 32..95 -----
  if (tid < ROWS * OUT_DIM) {           // 160 outputs
    const int r = tid / OUT_DIM;
    const int o = tid - r * OUT_DIM;
    float sacc = b_fc[o];
#pragma unroll
    for (int j = 0; j < HID; ++j)
      sacc += bf2f(hs[0][r][32 + j]) * W_fc[o * HID + j];
    out[(b0 + r) * OUT_DIM + o] = sacc;
  }
}

extern "C" void kernel_launch(void* const* d_in, const int* in_sizes, int n_in,
                              void* d_out, int out_size, void* d_ws, size_t ws_size,
                              hipStream_t stream) {
  const float* x    = (const float*)d_in[0];
  const float* W_ih = (const float*)d_in[1];
  const float* W_hh = (const float*)d_in[2];
  const float* b_ih = (const float*)d_in[3];
  const float* b_hh = (const float*)d_in[4];
  const float* W_fc = (const float*)d_in[5];
  const float* b_fc = (const float*)d_in[6];
  float* out = (float*)d_out;

  dim3 grid(B_TOT / ROWS);   // 1024 blocks -> 4 blocks/CU co-resident
  dim3 block(THREADS);
  lstm_mfma7<<<grid, block, 0, stream>>>(x, W_ih, W_hh, b_ih, b_hh, W_fc, b_fc, out);
}

// Round 9
// 132.318 us; speedup vs baseline: 1.0187x; 1.0187x over previous
//
#include <hip/hip_runtime.h>
#include <hip/hip_bf16.h>

// LSTM_71382356459716 R8: kill the gather prologue + rcp-paired activations.
// R7 post-mortem: de-phase/lockstep theory dead (flat). Unmodeled cost found:
// every block's A-frag init was 96 per-lane UNCOALESCED gathers (64-way
// divergent addresses, ~393k gather-instrs chip-wide, serial in the TA unit
// before any MFMA) -- consistent with OccupancyPercent 30% and the 26us idle.
// Fixes:
//  (1) setup kernel (every call) pre-permutes W_ih|bias|W_hh into exact frag
//      order (bf16) in d_ws (48KB); main-kernel A-init = 12 coalesced
//      global_load_dwordx4 per lane.
//  (2) activations: sigmoid pairs share one rcp (r=rcp(di*df); si=r*df,
//      sf=r*di), ditto (sigmoid(o), tanh(c)): 10 -> 8 trans per tuple,
//      algebraically exact; tanh argument clamped to +-15 (tanh==1.0 there)
//      so the pair product stays finite. c_state itself unclamped.
// Kept from R6/R7: 1024 blocks x 4 waves, wave owns 16 units (4 M-tiles
// stationary, bias folded into W col 28 vs constant-1 x column), 16 rows per
// block, balanced stagers (lanes 0..27 of each wave), two-deep x prefetch,
// double-buffered LDS rows of 104 shorts, 3 conflict-free ds_read_b128
// B-frags, 1 barrier/step, waves_per_eu(4,4).

namespace {
constexpr int B_TOT   = 16384;
constexpr int T_STEPS = 28;
constexpr int IN_DIM  = 28;
constexpr int HID     = 64;
constexpr int OUT_DIM = 10;
constexpr int ROWS    = 16;    // batch rows per block -> 1024 blocks, 4/CU
constexpr int THREADS = 256;   // 4 waves
constexpr int KP      = 104;   // row stride in shorts (208 B, odd*16B)
constexpr int XROW    = T_STEPS * IN_DIM;  // 784 floats per batch row
constexpr int NFRAG   = 16 * 3;            // (4 waves * 4 Mtiles) * 3 kchunks
constexpr int WS_ELEMS = NFRAG * 64 * 8;   // 24576 bf16 = 48 KB
}

typedef __attribute__((ext_vector_type(8))) short short8v;   // 8 bf16
typedef __attribute__((ext_vector_type(4))) short short4v;
typedef __attribute__((ext_vector_type(4))) float float4v;

__device__ __forceinline__ short f2bf_cold(float f) {
  union { float f; unsigned u; } v; v.f = f;
  unsigned r = v.u + 0x7FFFu + ((v.u >> 16) & 1u);
  return (short)(r >> 16);
}
__device__ __forceinline__ float bf2f(short s) {
  union { unsigned u; float f; } v; v.u = ((unsigned)(unsigned short)s) << 16;
  return v.f;
}
__device__ __forceinline__ unsigned pk2(float a, float b) {  // 2xf32->bf16x2
  __hip_bfloat162 h = __float22bfloat162_rn(float2{a, b});
  union { __hip_bfloat162 h; unsigned u; } cv; cv.h = h; return cv.u;
}

// ---- setup: permute weights+bias into MFMA A-frag order (runs every call) --
// ws layout: frag f = mt*3 + kc (mt = 4*w + i), lane l, elem j:
//   ws[(f*64 + l)*8 + j] = bf16 of A[m=16*mt+(l&15)][k=kc*32+(l>>4)*8+j]
// where gate row g = (m&3)*64 + (m>>2); k<28 -> W_ih, k==28 -> b_ih+b_hh,
// 29..31 -> 0, k>=32 -> W_hh[k-32].
__global__ void lstm_prep(const float* __restrict__ W_ih,
                          const float* __restrict__ W_hh,
                          const float* __restrict__ b_ih,
                          const float* __restrict__ b_hh,
                          unsigned short* __restrict__ ws) {
  int idx = blockIdx.x * blockDim.x + threadIdx.x;
  if (idx >= WS_ELEMS) return;
  int j  = idx & 7;
  int l  = (idx >> 3) & 63;
  int fk = idx >> 9;            // mt*3 + kc
  int kc = fk % 3;
  int mt = fk / 3;
  int m  = 16 * mt + (l & 15);
  int unit = m >> 2, type = m & 3;
  int g  = type * 64 + unit;
  int k  = kc * 32 + (l >> 4) * 8 + j;
  float v = 0.0f;
  if (k < IN_DIM)        v = W_ih[g * IN_DIM + k];
  else if (k == IN_DIM)  v = b_ih[g] + b_hh[g];
  else if (k >= 32)      v = W_hh[g * HID + (k - 32)];
  ws[idx] = (unsigned short)f2bf_cold(v);
}

__global__ __attribute__((amdgpu_flat_work_group_size(THREADS, THREADS),
                          amdgpu_waves_per_eu(4, 4)))
void lstm_mfma8(const float* __restrict__ x,
                const unsigned short* __restrict__ wfrag,
                const float* __restrict__ W_fc,
                const float* __restrict__ b_fc, float* __restrict__ out) {
  __shared__ short hs[2][ROWS][KP];   // [buf][row][k]: 0..27 x, 28 = 1.0, 32..95 h

  const int tid  = threadIdx.x;
  const int lane = tid & 63;
  const int w    = tid >> 6;      // wave 0..3 -> units 16w..16w+15
  const int l15  = lane & 15;
  const int q    = lane >> 4;     // 0..3
  const int b0   = blockIdx.x * ROWS;

  // ---- stationary A: 12 coalesced 16B loads per lane (frag-order from ws) --
  short8v a[4][3];
#pragma unroll
  for (int i = 0; i < 4; ++i)
#pragma unroll
    for (int kc = 0; kc < 3; ++kc)
      a[i][kc] = *(const short8v*)&wfrag[((((4 * w + i) * 3) + kc) * 64 + lane) * 8];

  // zero both buffers, then set the constant bias column (never overwritten)
  for (int idx = tid; idx < 2 * ROWS * KP; idx += THREADS) (&hs[0][0][0])[idx] = 0;
  __syncthreads();
  if (tid < 2 * ROWS) hs[tid >> 4][tid & 15][IN_DIM] = (short)0x3F80;  // bf16 1.0

  // ---- x staging balanced across waves: lanes 0..27 of each wave -----------
  const bool stager = (lane < 28);
  const int  s  = w * 28 + lane;
  const int  sr = s / 7;
  const int  sc = s - 7 * sr;
  const float* xptr = x + (size_t)(b0 + sr) * XROW + sc * 4;

  // stage x_0 directly; preload x_1 into the in-flight register
  float4 xfly = {0.f, 0.f, 0.f, 0.f};
  if (stager) {
    float4 x0 = *(const float4*)xptr;
    short4v sv;
    unsigned plo = pk2(x0.x, x0.y), phi = pk2(x0.z, x0.w);
    sv[0] = (short)(plo & 0xFFFF); sv[1] = (short)(plo >> 16);
    sv[2] = (short)(phi & 0xFFFF); sv[3] = (short)(phi >> 16);
    *(short4v*)&hs[0][sr][sc * 4] = sv;
    xfly = *(const float4*)(xptr + 1 * IN_DIM);   // x_1, consumed at t=0
  }
  __syncthreads();

  float c_state[4] = {0.f, 0.f, 0.f, 0.f};

  for (int t = 0; t < T_STEPS; ++t) {
    const int cur = t & 1, nxt = cur ^ 1;

    // B-frags: lane holds B[k = kc*32 + q*8 + j][n = l15]
    short8v bf0 = *(const short8v*)&hs[cur][l15][q * 8];
    short8v bf1 = *(const short8v*)&hs[cur][l15][32 + q * 8];
    short8v bf2 = *(const short8v*)&hs[cur][l15][64 + q * 8];

    // store x_{t+1} (loaded a full step ago), issue load of x_{t+2}
    if (stager) {
      if (t + 1 < T_STEPS) {
        short4v sv;
        unsigned plo = pk2(xfly.x, xfly.y), phi = pk2(xfly.z, xfly.w);
        sv[0] = (short)(plo & 0xFFFF); sv[1] = (short)(plo >> 16);
        sv[2] = (short)(phi & 0xFFFF); sv[3] = (short)(phi >> 16);
        *(short4v*)&hs[nxt][sr][sc * 4] = sv;
      }
      if (t + 2 < T_STEPS)
        xfly = *(const float4*)(xptr + (t + 2) * IN_DIM);
    }

    const float4v zero4 = {0.f, 0.f, 0.f, 0.f};
    float4v acc[4];
#pragma unroll
    for (int i = 0; i < 4; ++i)
      acc[i] = __builtin_amdgcn_mfma_f32_16x16x32_bf16(a[i][0], bf0, zero4, 0, 0, 0);
#pragma unroll
    for (int i = 0; i < 4; ++i)
      acc[i] = __builtin_amdgcn_mfma_f32_16x16x32_bf16(a[i][1], bf1, acc[i], 0, 0, 0);
#pragma unroll
    for (int i = 0; i < 4; ++i)
      acc[i] = __builtin_amdgcn_mfma_f32_16x16x32_bf16(a[i][2], bf2, acc[i], 0, 0, 0);

    // activations, rcp-paired; lane-local (regs 0..3 = i,f,g,o of one unit)
    float hv[4];
#pragma unroll
    for (int i = 0; i < 4; ++i) {
      float4v g4 = acc[i];
      float Ei = __expf(-g4[0]);
      float Ef = __expf(-g4[1]);
      float Eg = __expf(-2.0f * g4[2]);
      float Eo = __expf(-g4[3]);
      float di = 1.0f + Ei, df = 1.0f + Ef;
      float r1 = __builtin_amdgcn_rcpf(di * df);
      float iv = r1 * df;
      float fv = r1 * di;
      float gv = fmaf(2.0f, __builtin_amdgcn_rcpf(1.0f + Eg), -1.0f);
      float cn = fmaf(fv, c_state[i], iv * gv);
      c_state[i] = cn;
      float ct = fminf(fmaxf(cn, -15.0f), 15.0f);   // tanh saturated beyond
      float Ec = __expf(-2.0f * ct);
      float dn = 1.0f + Eo, dc = 1.0f + Ec;
      float r2 = __builtin_amdgcn_rcpf(dn * dc);
      float ov = r2 * dc;
      float tc = fmaf(2.0f * r2, dn, -1.0f);
      hv[i] = ov * tc;
    }
    // packed bf16 convert, 4 b16 stores (unit 16w+4i+q, row l15)
    unsigned p01 = pk2(hv[0], hv[1]);
    unsigned p23 = pk2(hv[2], hv[3]);
    hs[nxt][l15][32 + 16 * w + 0 + q]  = (short)(p01 & 0xFFFF);
    hs[nxt][l15][32 + 16 * w + 4 + q]  = (short)(p01 >> 16);
    hs[nxt][l15][32 + 16 * w + 8 + q]  = (short)(p23 & 0xFFFF);
    hs[nxt][l15][32 + 16 * w + 12 + q] = (short)(p23 >> 16);

    __syncthreads();
  }

  // ---- FC epilogue: final h in hs[0] (t=27 wrote nxt = 0), cols 32..95 -----
  if (tid < ROWS * OUT_DIM) {           // 160 outputs
    const int r = tid / OUT_DIM;
    const int o = tid - r * OUT_DIM;
    float sacc = b_fc[o];
#pragma unroll
    for (int j = 0; j < HID; ++j)
      sacc += bf2f(hs[0][r][32 + j]) * W_fc[o * HID + j];
    out[(b0 + r) * OUT_DIM + o] = sacc;
  }
}

extern "C" void kernel_launch(void* const* d_in, const int* in_sizes, int n_in,
                              void* d_out, int out_size, void* d_ws, size_t ws_size,
                              hipStream_t stream) {
  const float* x    = (const float*)d_in[0];
  const float* W_ih = (const float*)d_in[1];
  const float* W_hh = (const float*)d_in[2];
  const float* b_ih = (const float*)d_in[3];
  const float* b_hh = (const float*)d_in[4];
  const float* W_fc = (const float*)d_in[5];
  const float* b_fc = (const float*)d_in[6];
  float* out = (float*)d_out;
  unsigned short* ws = (unsigned short*)d_ws;   // 48 KB frag-ordered weights

  lstm_prep<<<(WS_ELEMS + 255) / 256, 256, 0, stream>>>(W_ih, W_hh, b_ih, b_hh, ws);

  dim3 grid(B_TOT / ROWS);   // 1024 blocks -> 4 blocks/CU co-resident
  dim3 block(THREADS);
  lstm_mfma8<<<grid, block, 0, stream>>>(x, ws, W_fc, b_fc, out);
}